// Round 1
// baseline (201.077 us; speedup 1.0000x reference)
//
#include <hip/hip_runtime.h>

#define B_ 16
#define T_ 1024
#define C_ 1024
#define T2_ (T_ + 2)
#define PAD_IDX_ 1
#define EPS_ 1e-5f

typedef float nfloat4 __attribute__((ext_vector_type(4)));

// Butterfly (sum,sumsq) across the 64 lanes of one wave. No LDS, no barrier.
__device__ __forceinline__ float2 wave_reduce_pair(float s, float q) {
    #pragma unroll
    for (int off = 32; off > 0; off >>= 1) {
        s += __shfl_xor(s, off, 64);
        q += __shfl_xor(q, off, 64);
    }
    return make_float2(s, q);
}

// One WAVE per output row (b, t) of (B, T+2, C): 16 floats/lane.
// 256-thread block = 4 independent rows; no __syncthreads anywhere.
__global__ __launch_bounds__(256) void fused_row_kernel(
        const float* __restrict__ x, const int* __restrict__ lengths,
        const float* __restrict__ bos, const float* __restrict__ eos,
        const float* __restrict__ sg, const float* __restrict__ sb,
        const float* __restrict__ pos_table, const float* __restrict__ scale,
        const float* __restrict__ g, const float* __restrict__ be,
        float* __restrict__ out, float* __restrict__ pad_out,
        float* __restrict__ l2_out) {
    const int wave = threadIdx.x >> 6;
    const int lane = threadIdx.x & 63;
    const int row  = blockIdx.x * 4 + wave;          // 16416 rows = 4104 * 4 exactly
    const int b = row / T2_;
    const int t = row - b * T2_;
    const int len = lengths[b];
    const int l1 = len + 1;
    const int l2 = len + 2;
    const int i0 = lane * 16;                        // 16 consecutive floats per lane
    const float inv_c = 1.0f / C_;

    nfloat4 v[4];
    if (t == 0 || t == l1) {
        // wave-uniform branch: LN_s(bos/eos) computed inline, wave-local reduce
        const float* src = (t == 0) ? bos : eos;
        float s = 0.f, q = 0.f;
        #pragma unroll
        for (int k = 0; k < 4; ++k) {
            v[k] = *(const nfloat4*)(src + i0 + 4 * k);
            s += v[k].x + v[k].y + v[k].z + v[k].w;
            q += v[k].x * v[k].x + v[k].y * v[k].y + v[k].z * v[k].z + v[k].w * v[k].w;
        }
        float2 r = wave_reduce_pair(s, q);
        float mu = r.x * inv_c;
        float rs = rsqrtf(r.y * inv_c - mu * mu + EPS_);
        #pragma unroll
        for (int k = 0; k < 4; ++k) {
            nfloat4 gv = *(const nfloat4*)(sg + i0 + 4 * k);
            nfloat4 bv = *(const nfloat4*)(sb + i0 + 4 * k);
            v[k] = (v[k] - mu) * rs * gv + bv;
        }
    } else if (t <= len) {
        // streaming read, no reuse: nontemporal to spare L2 for pos_table
        const nfloat4* p = (const nfloat4*)(x + ((size_t)b * T_ + (t - 1)) * (size_t)C_ + i0);
        #pragma unroll
        for (int k = 0; k < 4; ++k) v[k] = __builtin_nontemporal_load(p + k);
    } else {
        #pragma unroll
        for (int k = 0; k < 4; ++k) v[k] = (nfloat4)(0.f);
    }

    const int pos = (t < l2) ? (t + 2) : PAD_IDX_;
    const float sc = scale[0];
    const float* per = pos_table + (size_t)pos * C_ + i0;

    nfloat4 y[4];
    float s = 0.f, q = 0.f;
    #pragma unroll
    for (int k = 0; k < 4; ++k) {
        nfloat4 pe = *(const nfloat4*)(per + 4 * k);    // reused across b: keep cached
        y[k] = v[k] * sc + pe;
        s += y[k].x + y[k].y + y[k].z + y[k].w;
        q += y[k].x * y[k].x + y[k].y * y[k].y + y[k].z * y[k].z + y[k].w * y[k].w;
    }
    float2 r = wave_reduce_pair(s, q);
    float mu = r.x * inv_c;
    float rs = rsqrtf(r.y * inv_c - mu * mu + EPS_);

    nfloat4* outp = (nfloat4*)(out + (size_t)row * C_ + i0);
    #pragma unroll
    for (int k = 0; k < 4; ++k) {
        nfloat4 gv = *(const nfloat4*)(g + i0 + 4 * k);
        nfloat4 bv = *(const nfloat4*)(be + i0 + 4 * k);
        __builtin_nontemporal_store((y[k] - mu) * rs * gv + bv, outp + k);
    }

    if (lane == 0) {
        pad_out[row] = (t >= l2) ? 1.0f : 0.0f;
        if (t == 0) l2_out[b] = (float)l2;
    }
}

extern "C" void kernel_launch(void* const* d_in, const int* in_sizes, int n_in,
                              void* d_out, int out_size, void* d_ws, size_t ws_size,
                              hipStream_t stream) {
    const float* x         = (const float*)d_in[0];
    const int*   lengths   = (const int*)d_in[1];
    const float* bos_emb   = (const float*)d_in[2];
    const float* eos_emb   = (const float*)d_in[3];
    const float* ln_s_g    = (const float*)d_in[4];
    const float* ln_s_b    = (const float*)d_in[5];
    const float* pos_table = (const float*)d_in[6];
    const float* scale     = (const float*)d_in[7];
    const float* ln_e_g    = (const float*)d_in[8];
    const float* ln_e_b    = (const float*)d_in[9];

    float* out = (float*)d_out;
    float* pad_out = out + (size_t)B_ * T2_ * C_;
    float* l2_out  = pad_out + (size_t)B_ * T2_;

    fused_row_kernel<<<(B_ * T2_) / 4, 256, 0, stream>>>(
        x, lengths, bos_emb, eos_emb, ln_s_g, ln_s_b, pos_table, scale,
        ln_e_g, ln_e_b, out, pad_out, l2_out);
}

// Round 2
// 140.431 us; speedup vs baseline: 1.4319x; 1.4319x over previous
//
#include <hip/hip_runtime.h>

#define B_ 16
#define T_ 1024
#define C_ 1024
#define T2_ (T_ + 2)
#define PAD_IDX_ 1
#define EPS_ 1e-5f

typedef float nfloat4 __attribute__((ext_vector_type(4)));

// Butterfly (sum,sumsq) across the 64 lanes of one wave. No LDS, no barrier.
__device__ __forceinline__ float2 wave_reduce_pair(float s, float q) {
    #pragma unroll
    for (int off = 32; off > 0; off >>= 1) {
        s += __shfl_xor(s, off, 64);
        q += __shfl_xor(q, off, 64);
    }
    return make_float2(s, q);
}

// One WAVE per output row (b, t) of (B, T+2, C).
// Lane-INTERLEAVED layout: chunk k covers elements (k*64+lane)*4 .. +3,
// so every load/store instruction spans 1024 contiguous bytes (full coalescing).
// 256-thread block = 4 independent rows; no __syncthreads anywhere.
__global__ __launch_bounds__(256) void fused_row_kernel(
        const float* __restrict__ x, const int* __restrict__ lengths,
        const float* __restrict__ bos, const float* __restrict__ eos,
        const float* __restrict__ sg, const float* __restrict__ sb,
        const float* __restrict__ pos_table, const float* __restrict__ scale,
        const float* __restrict__ g, const float* __restrict__ be,
        float* __restrict__ out, float* __restrict__ pad_out,
        float* __restrict__ l2_out) {
    const int wave = threadIdx.x >> 6;
    const int lane = threadIdx.x & 63;
    const int row  = blockIdx.x * 4 + wave;          // 16416 rows = 4104 * 4 exactly
    const int b = row / T2_;
    const int t = row - b * T2_;
    const int len = lengths[b];
    const int l1 = len + 1;
    const int l2 = len + 2;
    const float inv_c = 1.0f / C_;

    // element offsets for the 4 chunks this lane owns (each a float4)
    int e[4];
    #pragma unroll
    for (int k = 0; k < 4; ++k) e[k] = (k * 64 + lane) * 4;

    nfloat4 v[4];
    if (t == 0 || t == l1) {
        // wave-uniform branch: LN_s(bos/eos) computed inline, wave-local reduce
        const float* src = (t == 0) ? bos : eos;
        float s = 0.f, q = 0.f;
        #pragma unroll
        for (int k = 0; k < 4; ++k) {
            v[k] = *(const nfloat4*)(src + e[k]);
            s += v[k].x + v[k].y + v[k].z + v[k].w;
            q += v[k].x * v[k].x + v[k].y * v[k].y + v[k].z * v[k].z + v[k].w * v[k].w;
        }
        float2 r = wave_reduce_pair(s, q);
        float mu = r.x * inv_c;
        float rs = rsqrtf(r.y * inv_c - mu * mu + EPS_);
        #pragma unroll
        for (int k = 0; k < 4; ++k) {
            nfloat4 gv = *(const nfloat4*)(sg + e[k]);
            nfloat4 bv = *(const nfloat4*)(sb + e[k]);
            v[k] = (v[k] - mu) * rs * gv + bv;
        }
    } else if (t <= len) {
        // streaming read, no reuse: nontemporal to spare L2 for pos_table
        const float* xrow = x + ((size_t)b * T_ + (t - 1)) * (size_t)C_;
        #pragma unroll
        for (int k = 0; k < 4; ++k)
            v[k] = __builtin_nontemporal_load((const nfloat4*)(xrow + e[k]));
    } else {
        #pragma unroll
        for (int k = 0; k < 4; ++k) v[k] = (nfloat4)(0.f);
    }

    const int pos = (t < l2) ? (t + 2) : PAD_IDX_;
    const float sc = scale[0];
    const float* per = pos_table + (size_t)pos * C_;

    nfloat4 y[4];
    float s = 0.f, q = 0.f;
    #pragma unroll
    for (int k = 0; k < 4; ++k) {
        nfloat4 pe = *(const nfloat4*)(per + e[k]);     // reused across b: keep cached
        y[k] = v[k] * sc + pe;
        s += y[k].x + y[k].y + y[k].z + y[k].w;
        q += y[k].x * y[k].x + y[k].y * y[k].y + y[k].z * y[k].z + y[k].w * y[k].w;
    }
    float2 r = wave_reduce_pair(s, q);
    float mu = r.x * inv_c;
    float rs = rsqrtf(r.y * inv_c - mu * mu + EPS_);

    float* outrow = out + (size_t)row * C_;
    #pragma unroll
    for (int k = 0; k < 4; ++k) {
        nfloat4 gv = *(const nfloat4*)(g + e[k]);
        nfloat4 bv = *(const nfloat4*)(be + e[k]);
        __builtin_nontemporal_store((y[k] - mu) * rs * gv + bv,
                                    (nfloat4*)(outrow + e[k]));
    }

    if (lane == 0) {
        pad_out[row] = (t >= l2) ? 1.0f : 0.0f;
        if (t == 0) l2_out[b] = (float)l2;
    }
}

extern "C" void kernel_launch(void* const* d_in, const int* in_sizes, int n_in,
                              void* d_out, int out_size, void* d_ws, size_t ws_size,
                              hipStream_t stream) {
    const float* x         = (const float*)d_in[0];
    const int*   lengths   = (const int*)d_in[1];
    const float* bos_emb   = (const float*)d_in[2];
    const float* eos_emb   = (const float*)d_in[3];
    const float* ln_s_g    = (const float*)d_in[4];
    const float* ln_s_b    = (const float*)d_in[5];
    const float* pos_table = (const float*)d_in[6];
    const float* scale     = (const float*)d_in[7];
    const float* ln_e_g    = (const float*)d_in[8];
    const float* ln_e_b    = (const float*)d_in[9];

    float* out = (float*)d_out;
    float* pad_out = out + (size_t)B_ * T2_ * C_;
    float* l2_out  = pad_out + (size_t)B_ * T2_;

    fused_row_kernel<<<(B_ * T2_) / 4, 256, 0, stream>>>(
        x, lengths, bos_emb, eos_emb, ln_s_g, ln_s_b, pos_table, scale,
        ln_e_g, ln_e_b, out, pad_out, l2_out);
}